// Round 6
// baseline (286.157 us; speedup 1.0000x reference)
//
#include <hip/hip_runtime.h>
#include <hip/hip_bf16.h>

// x [4,2048,1024] fp32; Wq/Wk/Wv [1024,1024] fp32. Causal attention.
// Algebra: scores = x Wq Wk^T x^T = T x^T with T = x M'^T, M' = Wk Wq^T.
#define NB 4
#define SB 2048
#define DD 1024
#define BM 128
#define BN 128
#define BK 32

typedef __attribute__((ext_vector_type(8))) short bf16x8;
typedef __attribute__((ext_vector_type(4))) short bf16x4;
typedef __attribute__((ext_vector_type(4))) float f32x4;
typedef unsigned int u32;

__device__ __forceinline__ float bf2f(unsigned short u) {
    return __uint_as_float(((u32)u) << 16);
}
__device__ __forceinline__ short f2bf(float f) {
    u32 u = __float_as_uint(f);
    u32 r = (u + 0x7fffu + ((u >> 16) & 1u)) >> 16;
    return (short)r;
}

// ---------------------------------------------------------------------------
// MFMA tile step shared by all GEMM kernels: frag loads from LDS + 16 MFMAs.
// LDS layout: row-major [128][BK] bf16.
// ---------------------------------------------------------------------------
__device__ __forceinline__ void mfma_step(const short* As, const short* Bs,
                                          f32x4 (&acc)[4][4], int lane, int wave)
{
    const int wm = (wave >> 1) * 64, wn = (wave & 1) * 64;
    const int fr = lane & 15;
    const int quad = lane >> 4;
    bf16x8 af[4], bf[4];
#pragma unroll
    for (int t = 0; t < 4; t++) {
        af[t] = *(const bf16x8*)&As[(wm + t * 16 + fr) * BK + quad * 8];
        bf[t] = *(const bf16x8*)&Bs[(wn + t * 16 + fr) * BK + quad * 8];
    }
#pragma unroll
    for (int mt = 0; mt < 4; mt++)
#pragma unroll
        for (int nt = 0; nt < 4; nt++)
            acc[mt][nt] = __builtin_amdgcn_mfma_f32_16x16x32_bf16(
                af[mt], bf[nt], acc[mt][nt], 0, 0, 0);
}

// bf16 source staging via async global->LDS, 16B/lane x 2.
__device__ __forceinline__ void stage128x32(const short* __restrict__ g, int ld,
                                            short* lds, int tid) {
    const int wave = tid >> 6, lane = tid & 63;
    const int r = lane >> 2;
    const int c = (lane & 3) * 8;
#pragma unroll
    for (int i = 0; i < 2; i++) {
        const int chunk = wave * 2 + i;
        const short* gp = g + (size_t)(chunk * 16 + r) * ld + c;
        __builtin_amdgcn_global_load_lds(
            (const __attribute__((address_space(1))) u32*)gp,
            (__attribute__((address_space(3))) u32*)(lds + chunk * 512 + lane * 8),
            16, 0, 0);
    }
}

// fp32 source staging: load fp32, convert, ds_write (for the fused mm blocks).
__device__ __forceinline__ void stage_f32_128x32(const float* __restrict__ g,
                                                 int ld, short* lds, int tid) {
    const int r = tid >> 1;
    const int c = (tid & 1) * 16;
    const float* gp = &g[(size_t)r * ld + c];
    float4 v0 = *(const float4*)(gp + 0);
    float4 v1 = *(const float4*)(gp + 4);
    float4 v2 = *(const float4*)(gp + 8);
    float4 v3 = *(const float4*)(gp + 12);
    bf16x8 o0, o1;
    o0[0] = f2bf(v0.x); o0[1] = f2bf(v0.y); o0[2] = f2bf(v0.z); o0[3] = f2bf(v0.w);
    o0[4] = f2bf(v1.x); o0[5] = f2bf(v1.y); o0[6] = f2bf(v1.z); o0[7] = f2bf(v1.w);
    o1[0] = f2bf(v2.x); o1[1] = f2bf(v2.y); o1[2] = f2bf(v2.z); o1[3] = f2bf(v2.w);
    o1[4] = f2bf(v3.x); o1[5] = f2bf(v3.y); o1[6] = f2bf(v3.z); o1[7] = f2bf(v3.w);
    *(bf16x8*)&lds[r * BK + c] = o0;
    *(bf16x8*)&lds[r * BK + c + 8] = o1;
}

__device__ __forceinline__ void gemm_bt_body(
    const short* __restrict__ A, int lda, const short* __restrict__ Bt, int ldb,
    int m0, int n0, int kend, short* As, short* Bs, f32x4 (&acc)[4][4], int tid)
{
    const int lane = tid & 63;
    const int wave = tid >> 6;
    for (int k0 = 0; k0 < kend; k0 += BK) {
        stage128x32(A + (size_t)m0 * lda + k0, lda, As, tid);
        stage128x32(Bt + (size_t)n0 * ldb + k0, ldb, Bs, tid);
        __syncthreads();
        mfma_step(As, Bs, acc, lane, wave);
        __syncthreads();
    }
}

// ---------------------------------------------------------------------------
// Fused prep + mm:
//   bx in [0,64):        M' = Wk . Wq^T (self-casting fp32 staging) -> Mp bf16
//                        (latency hidden under the 4096 streaming cast blocks)
//   bx in [64,4160):     cast x fp32->bf16 (8 elem/thr)
//   bx in [4160,4416):   cast+transpose Wv -> Wvt[n][k]
// ---------------------------------------------------------------------------
__global__ __launch_bounds__(256) void prep_mm(
    const float* __restrict__ x, const float* __restrict__ Wq,
    const float* __restrict__ Wk, const float* __restrict__ Wv,
    short* __restrict__ xb, short* __restrict__ Wvt, short* __restrict__ Mp)
{
    __shared__ short As[BM * BK], Bs[BN * BK];
    __shared__ short t[64][65];
    const int bx = blockIdx.x;
    const int tid = threadIdx.x;
    if (bx < 64) {
        // --- M' block: Mp[l][k] = sum_n Wk[l][n] Wq[k][n]
        const int m0 = (bx >> 3) * BM;
        const int n0 = (bx & 7) * BN;
        const int lane = tid & 63, wave = tid >> 6;
        f32x4 acc[4][4];
#pragma unroll
        for (int a = 0; a < 4; a++)
#pragma unroll
            for (int b = 0; b < 4; b++) acc[a][b] = (f32x4){0.f, 0.f, 0.f, 0.f};
        for (int k0 = 0; k0 < DD; k0 += BK) {
            stage_f32_128x32(Wk + (size_t)m0 * DD + k0, DD, As, tid);
            stage_f32_128x32(Wq + (size_t)n0 * DD + k0, DD, Bs, tid);
            __syncthreads();
            mfma_step(As, Bs, acc, lane, wave);
            __syncthreads();
        }
        const int wm = (wave >> 1) * 64, wn = (wave & 1) * 64;
        const int fr = lane & 15, quad = lane >> 4;
#pragma unroll
        for (int mt = 0; mt < 4; mt++)
#pragma unroll
            for (int nt = 0; nt < 4; nt++)
#pragma unroll
                for (int r = 0; r < 4; r++) {
                    const size_t m = m0 + wm + mt * 16 + quad * 4 + r;
                    const size_t n = n0 + wn + nt * 16 + fr;
                    Mp[m * DD + n] = f2bf(acc[mt][nt][r]);
                }
        return;
    }
    if (bx < 4160) {
        const size_t i = ((size_t)(bx - 64) * 256 + tid) * 8;
        float4 a = *(const float4*)&x[i];
        float4 b = *(const float4*)&x[i + 4];
        bf16x8 o;
        o[0] = f2bf(a.x); o[1] = f2bf(a.y); o[2] = f2bf(a.z); o[3] = f2bf(a.w);
        o[4] = f2bf(b.x); o[5] = f2bf(b.y); o[6] = f2bf(b.z); o[7] = f2bf(b.w);
        *(bf16x8*)&xb[i] = o;
        return;
    }
    const int rr = bx - 4160;
    const int k0 = (rr & 15) * 64;
    const int n0 = (rr >> 4) * 64;
    {
        const int r = tid >> 4;
        const int c = (tid & 15) * 4;
#pragma unroll
        for (int i = 0; i < 4; i++) {
            float4 v = *(const float4*)&Wv[(size_t)(k0 + i * 16 + r) * DD + n0 + c];
            t[i * 16 + r][c + 0] = f2bf(v.x);
            t[i * 16 + r][c + 1] = f2bf(v.y);
            t[i * 16 + r][c + 2] = f2bf(v.z);
            t[i * 16 + r][c + 3] = f2bf(v.w);
        }
    }
    __syncthreads();
    {
        const int r = tid >> 3;
        const int c = (tid & 7) * 8;
#pragma unroll
        for (int i = 0; i < 2; i++) {
            bf16x8 o;
#pragma unroll
            for (int j = 0; j < 8; j++) o[j] = t[c + j][i * 32 + r];
            *(bf16x8*)&Wvt[(size_t)(n0 + i * 32 + r) * DD + k0 + c] = o;
        }
    }
}

// ---------------------------------------------------------------------------
// T = xb . M'^T, row-major bf16. Lean epilogue (qkv clone).
// ---------------------------------------------------------------------------
__global__ __launch_bounds__(256) void t_gemm(
    const short* __restrict__ xb, const short* __restrict__ Mp,
    short* __restrict__ T)
{
    __shared__ short As[BM * BK], Bs[BN * BK];
    const int n0 = blockIdx.x * BN;
    const int m0 = blockIdx.y * BM;
    f32x4 acc[4][4];
#pragma unroll
    for (int a = 0; a < 4; a++)
#pragma unroll
        for (int b = 0; b < 4; b++) acc[a][b] = (f32x4){0.f, 0.f, 0.f, 0.f};
    gemm_bt_body(xb, DD, Mp, DD, m0, n0, DD, As, Bs, acc, threadIdx.x);
    const int lane = threadIdx.x & 63, wave = threadIdx.x >> 6;
    const int wm = (wave >> 1) * 64, wn = (wave & 1) * 64;
    const int fr = lane & 15, quad = lane >> 4;
#pragma unroll
    for (int mt = 0; mt < 4; mt++)
#pragma unroll
        for (int nt = 0; nt < 4; nt++)
#pragma unroll
            for (int r = 0; r < 4; r++) {
                const size_t m = m0 + wm + mt * 16 + quad * 4 + r;
                const size_t n = n0 + wn + nt * 16 + fr;
                T[m * DD + n] = f2bf(acc[mt][nt][r]);
            }
}

// ---------------------------------------------------------------------------
// V = xb . Wvt^T, stored TRANSPOSED directly as Vt[b][n][s]
// (lane packs its 4 consecutive-s accs into one 8B store).
// ---------------------------------------------------------------------------
__global__ __launch_bounds__(256) void v_gemm(
    const short* __restrict__ xb, const short* __restrict__ Wvt,
    short* __restrict__ Vt)
{
    __shared__ short As[BM * BK], Bs[BN * BK];
    const int n0 = blockIdx.x * BN;
    const int m0 = blockIdx.y * BM;
    f32x4 acc[4][4];
#pragma unroll
    for (int a = 0; a < 4; a++)
#pragma unroll
        for (int b = 0; b < 4; b++) acc[a][b] = (f32x4){0.f, 0.f, 0.f, 0.f};
    gemm_bt_body(xb, DD, Wvt, DD, m0, n0, DD, As, Bs, acc, threadIdx.x);
    const int lane = threadIdx.x & 63, wave = threadIdx.x >> 6;
    const int wm = (wave >> 1) * 64, wn = (wave & 1) * 64;
    const int fr = lane & 15, quad = lane >> 4;
    const int bb = m0 >> 11;                       // batch of this m-tile
    const int s0 = (m0 & (SB - 1)) + wm + quad * 4;
    short* Vb = Vt + (size_t)bb * DD * SB;
#pragma unroll
    for (int mt = 0; mt < 4; mt++)
#pragma unroll
        for (int nt = 0; nt < 4; nt++) {
            const size_t n = n0 + wn + nt * 16 + fr;
            const size_t s = s0 + mt * 16;
            bf16x4 o;
#pragma unroll
            for (int r = 0; r < 4; r++) o[r] = f2bf(acc[mt][nt][r]);
            *(bf16x4*)&Vb[n * SB + s] = o;
        }
}

// ---------------------------------------------------------------------------
// Scores: compact triangular grid — blockIdx.x in [0,136) -> (qt,kt), kt<=qt.
// Sc[b][q][j] = scale * T_b[q,:] . xb_b[j,:], bf16 out.
// ---------------------------------------------------------------------------
__global__ __launch_bounds__(256) void scores_mfma(
    const short* __restrict__ T, const short* __restrict__ xb,
    short* __restrict__ Sc)
{
    const int idx = blockIdx.x;
    int qt = (int)((__fsqrt_rn(8.f * idx + 1.f) - 1.f) * 0.5f);
    while ((qt + 1) * (qt + 2) / 2 <= idx) qt++;
    while (qt * (qt + 1) / 2 > idx) qt--;
    const int kt = idx - qt * (qt + 1) / 2;
    const int qm0 = qt * BM;
    const int kn0 = kt * BN;
    const int b = blockIdx.y;
    __shared__ short As[BM * BK], Bs[BN * BK];
    const short* Tb = T + (size_t)b * SB * DD;
    const short* Xb = xb + (size_t)b * SB * DD;
    short* Sb = Sc + (size_t)b * SB * SB;
    f32x4 acc[4][4];
#pragma unroll
    for (int a = 0; a < 4; a++)
#pragma unroll
        for (int c = 0; c < 4; c++) acc[a][c] = (f32x4){0.f, 0.f, 0.f, 0.f};
    gemm_bt_body(Tb, DD, Xb, DD, qm0, kn0, DD, As, Bs, acc, threadIdx.x);
    const int lane = threadIdx.x & 63, wave = threadIdx.x >> 6;
    const int wm = (wave >> 1) * 64, wn = (wave & 1) * 64;
    const int fr = lane & 15, quad = lane >> 4;
    const float scale = 0.03125f;  // 1/sqrt(1024)
#pragma unroll
    for (int mt = 0; mt < 4; mt++)
#pragma unroll
        for (int nt = 0; nt < 4; nt++)
#pragma unroll
            for (int r = 0; r < 4; r++) {
                const size_t q = qm0 + wm + mt * 16 + quad * 4 + r;
                const size_t k = kn0 + wn + nt * 16 + fr;
                Sb[q * SB + k] = f2bf(acc[mt][nt][r] * scale);
            }
}

// ---------------------------------------------------------------------------
// Causal softmax on bf16 scores, in place (row stride SB shorts). Row i only
// touches j < jlim = (i/128+1)*128 — pv reads exactly k < (qt+1)*128.
// ---------------------------------------------------------------------------
__global__ __launch_bounds__(256) void softmax_kernel(short* __restrict__ Sc)
{
    const int row = blockIdx.x;
    const int i = row & (SB - 1);
    const int jlim = ((i >> 7) + 1) << 7;
    short* r = Sc + (size_t)row * SB;
    const int t = threadIdx.x;
    const int lane = t & 63, wave = t >> 6;
    __shared__ float red[8];

    float v[8];
    float mx = -1e30f;
#pragma unroll
    for (int c = 0; c < 8; c++) {
        const int j = c * 256 + t;
        const float s = (j <= i) ? bf2f((unsigned short)r[j]) : -1e30f;
        v[c] = s;
        mx = fmaxf(mx, s);
    }
#pragma unroll
    for (int o = 32; o > 0; o >>= 1) mx = fmaxf(mx, __shfl_down(mx, o));
    if (lane == 0) red[wave] = mx;
    __syncthreads();
    mx = fmaxf(fmaxf(red[0], red[1]), fmaxf(red[2], red[3]));

    float sum = 0.f;
#pragma unroll
    for (int c = 0; c < 8; c++) {
        const int j = c * 256 + t;
        const float e = (j <= i) ? __expf(v[c] - mx) : 0.f;
        v[c] = e;
        sum += e;
    }
#pragma unroll
    for (int o = 32; o > 0; o >>= 1) sum += __shfl_down(sum, o);
    if (lane == 0) red[4 + wave] = sum;
    __syncthreads();
    const float inv = 1.0f / (red[4] + red[5] + red[6] + red[7]);
#pragma unroll
    for (int c = 0; c < 8; c++) {
        const int j = c * 256 + t;
        if (j < jlim) r[j] = f2bf(v[c] * inv);
    }
}

// ---------------------------------------------------------------------------
// PV split-k, atomic-free. blockIdx.y in [0,24):
//   y<16:  qt=y, k in [0, min(1024,(qt+1)*128))  -> store DIRECT to out
//   y>=16: qt=y-8, k in [1024, (qt+1)*128)       -> store to partial Pp
// All blocks <= 32 k-iters. reduce_pv adds Pp into out's upper half.
// ---------------------------------------------------------------------------
__global__ __launch_bounds__(256) void pv_mfma(
    const short* __restrict__ P, const short* __restrict__ Vt,
    float* __restrict__ O, float* __restrict__ Pp)
{
    __shared__ short As[BM * BK], Bs[BN * BK];
    const int n0 = blockIdx.x * BN;
    const int y = blockIdx.y;
    const int chunk1 = (y >= 16);
    const int qt = chunk1 ? (y - 8) : y;
    const int qm0 = qt * BM;
    const int kstart = chunk1 ? 1024 : 0;
    const int kstop = chunk1 ? (qt + 1) * BM : min(1024, (qt + 1) * BM);
    const int b = blockIdx.z;
    const short* Pb = P + (size_t)b * SB * SB + kstart;
    const short* Vb = Vt + (size_t)b * DD * SB + kstart;
    f32x4 acc[4][4];
#pragma unroll
    for (int a = 0; a < 4; a++)
#pragma unroll
        for (int c = 0; c < 4; c++) acc[a][c] = (f32x4){0.f, 0.f, 0.f, 0.f};
    gemm_bt_body(Pb, SB, Vb, SB, qm0, n0, kstop - kstart, As, Bs, acc,
                 threadIdx.x);
    const int lane = threadIdx.x & 63, wave = threadIdx.x >> 6;
    const int wm = (wave >> 1) * 64, wn = (wave & 1) * 64;
    const int fr = lane & 15, quad = lane >> 4;
    float* dst = chunk1 ? (Pp + (size_t)b * 1024 * DD)
                        : (O + (size_t)b * SB * DD);
    const int qoff = chunk1 ? 1024 : 0;
#pragma unroll
    for (int mt = 0; mt < 4; mt++)
#pragma unroll
        for (int nt = 0; nt < 4; nt++)
#pragma unroll
            for (int r = 0; r < 4; r++) {
                const size_t q = qm0 + wm + mt * 16 + quad * 4 + r - qoff;
                const size_t n = n0 + wn + nt * 16 + fr;
                dst[q * DD + n] = acc[mt][nt][r];
            }
}

// ---------------------------------------------------------------------------
// reduce: O[b][1024+q'][:] += Pp[b][q'][:], 4 floats/thread.
// ---------------------------------------------------------------------------
__global__ __launch_bounds__(256) void reduce_pv(const float* __restrict__ Pp,
                                                 float* __restrict__ O)
{
    const size_t e = ((size_t)blockIdx.x * 256 + threadIdx.x) * 4;
    const size_t b = e / ((size_t)1024 * DD);
    const size_t rem = e - b * (size_t)1024 * DD;
    float4 p = *(const float4*)&Pp[e];
    float* o = &O[b * (size_t)SB * DD + (size_t)1024 * DD + rem];
    float4 v = *(const float4*)o;
    v.x += p.x; v.y += p.y; v.z += p.z; v.w += p.w;
    *(float4*)o = v;
}

extern "C" void kernel_launch(void* const* d_in, const int* in_sizes, int n_in,
                              void* d_out, int out_size, void* d_ws, size_t ws_size,
                              hipStream_t stream)
{
    const float* x  = (const float*)d_in[0];
    const float* Wq = (const float*)d_in[1];
    const float* Wk = (const float*)d_in[2];
    const float* Wv = (const float*)d_in[3];
    float* out = (float*)d_out;

    // ws layout, all disjoint (~105 MB < 117.44 MB known-available):
    // [xb 16.8M][T 16.8M][Vt 16.8M][Sc 33.6M][Pp 16.8M][Wvt 2M][Mp 2M]
    const size_t XE = (size_t)NB * SB * DD;   // 8.39M elems
    const size_t WE = (size_t)DD * DD;        // 1.05M elems
    short* xb  = (short*)d_ws;
    short* T   = xb + XE;
    short* Vt  = T + XE;
    short* Sc  = Vt + XE;                     // NB*SB*SB shorts
    float* Pp  = (float*)(Sc + (size_t)NB * SB * SB);
    short* Wvt = (short*)(Pp + (size_t)NB * 1024 * DD);
    short* Mp  = Wvt + WE;

    prep_mm<<<dim3(64 + 4096 + 256), 256, 0, stream>>>(
        x, Wq, Wk, Wv, xb, Wvt, Mp);
    t_gemm<<<dim3(DD / BN, (NB * SB) / BM), 256, 0, stream>>>(xb, Mp, T);
    v_gemm<<<dim3(DD / BN, (NB * SB) / BM), 256, 0, stream>>>(xb, Wvt, Vt);
    scores_mfma<<<dim3(136, NB), 256, 0, stream>>>(T, xb, Sc);
    softmax_kernel<<<dim3(NB * SB), 256, 0, stream>>>(Sc);
    pv_mfma<<<dim3(DD / BN, 24, NB), 256, 0, stream>>>(Sc, Vt, out, Pp);
    reduce_pv<<<dim3((unsigned)((size_t)NB * 1024 * DD / 4 / 256)), 256, 0,
                stream>>>(Pp, out);
}

// Round 7
// 265.717 us; speedup vs baseline: 1.0769x; 1.0769x over previous
//
#include <hip/hip_runtime.h>
#include <hip/hip_bf16.h>

// x [4,2048,1024] fp32; Wq/Wk/Wv [1024,1024] fp32. Causal attention.
// Algebra: scores = x Wq Wk^T x^T = T x^T with T = x M'^T, M' = Wk Wq^T.
#define NB 4
#define SB 2048
#define DD 1024
#define BM 128
#define BN 128
#define BK 32

typedef __attribute__((ext_vector_type(8))) short bf16x8;
typedef __attribute__((ext_vector_type(4))) short bf16x4;
typedef __attribute__((ext_vector_type(4))) float f32x4;
typedef unsigned int u32;

__device__ __forceinline__ float bf2f(unsigned short u) {
    return __uint_as_float(((u32)u) << 16);
}
__device__ __forceinline__ short f2bf(float f) {
    u32 u = __float_as_uint(f);
    u32 r = (u + 0x7fffu + ((u >> 16) & 1u)) >> 16;
    return (short)r;
}

// ---------------------------------------------------------------------------
// MFMA tile step: frag loads from LDS ([128][BK] row-major) + 16 MFMAs.
// ---------------------------------------------------------------------------
__device__ __forceinline__ void mfma_step(const short* As, const short* Bs,
                                          f32x4 (&acc)[4][4], int lane, int wave)
{
    const int wm = (wave >> 1) * 64, wn = (wave & 1) * 64;
    const int fr = lane & 15;
    const int quad = lane >> 4;
    bf16x8 af[4], bf[4];
#pragma unroll
    for (int t = 0; t < 4; t++) {
        af[t] = *(const bf16x8*)&As[(wm + t * 16 + fr) * BK + quad * 8];
        bf[t] = *(const bf16x8*)&Bs[(wn + t * 16 + fr) * BK + quad * 8];
    }
#pragma unroll
    for (int mt = 0; mt < 4; mt++)
#pragma unroll
        for (int nt = 0; nt < 4; nt++)
            acc[mt][nt] = __builtin_amdgcn_mfma_f32_16x16x32_bf16(
                af[mt], bf[nt], acc[mt][nt], 0, 0, 0);
}

// bf16 source staging via async global->LDS, 16B/lane x 2.
__device__ __forceinline__ void stage128x32(const short* __restrict__ g, int ld,
                                            short* lds, int tid) {
    const int wave = tid >> 6, lane = tid & 63;
    const int r = lane >> 2;
    const int c = (lane & 3) * 8;
#pragma unroll
    for (int i = 0; i < 2; i++) {
        const int chunk = wave * 2 + i;
        const short* gp = g + (size_t)(chunk * 16 + r) * ld + c;
        __builtin_amdgcn_global_load_lds(
            (const __attribute__((address_space(1))) u32*)gp,
            (__attribute__((address_space(3))) u32*)(lds + chunk * 512 + lane * 8),
            16, 0, 0);
    }
}

// fp32 source staging: load fp32, convert, ds_write (for the fused mm blocks).
__device__ __forceinline__ void stage_f32_128x32(const float* __restrict__ g,
                                                 int ld, short* lds, int tid) {
    const int r = tid >> 1;
    const int c = (tid & 1) * 16;
    const float* gp = &g[(size_t)r * ld + c];
    float4 v0 = *(const float4*)(gp + 0);
    float4 v1 = *(const float4*)(gp + 4);
    float4 v2 = *(const float4*)(gp + 8);
    float4 v3 = *(const float4*)(gp + 12);
    bf16x8 o0, o1;
    o0[0] = f2bf(v0.x); o0[1] = f2bf(v0.y); o0[2] = f2bf(v0.z); o0[3] = f2bf(v0.w);
    o0[4] = f2bf(v1.x); o0[5] = f2bf(v1.y); o0[6] = f2bf(v1.z); o0[7] = f2bf(v1.w);
    o1[0] = f2bf(v2.x); o1[1] = f2bf(v2.y); o1[2] = f2bf(v2.z); o1[3] = f2bf(v2.w);
    o1[4] = f2bf(v3.x); o1[5] = f2bf(v3.y); o1[6] = f2bf(v3.z); o1[7] = f2bf(v3.w);
    *(bf16x8*)&lds[r * BK + c] = o0;
    *(bf16x8*)&lds[r * BK + c + 8] = o1;
}

__device__ __forceinline__ void gemm_bt_body(
    const short* __restrict__ A, int lda, const short* __restrict__ Bt, int ldb,
    int m0, int n0, int kend, short* As, short* Bs, f32x4 (&acc)[4][4], int tid)
{
    const int lane = tid & 63;
    const int wave = tid >> 6;
    for (int k0 = 0; k0 < kend; k0 += BK) {
        stage128x32(A + (size_t)m0 * lda + k0, lda, As, tid);
        stage128x32(Bt + (size_t)n0 * ldb + k0, ldb, Bs, tid);
        __syncthreads();
        mfma_step(As, Bs, acc, lane, wave);
        __syncthreads();
    }
}

// ---------------------------------------------------------------------------
// Fused prep + split-k mm:
//   bx in [0,256):       M' partials: chunk c=bx>>6 computes
//                        Mp4[c][m][n] = sum_{k in c*256..+256} Wk[m][k]Wq[n][k]
//                        (8-iter chain — hidden under the cast streaming)
//   bx in [256,4352):    cast x fp32->bf16 (8 elem/thr)
//   bx in [4352,4608):   cast+transpose Wv -> Wvt[n][k]
// ---------------------------------------------------------------------------
__global__ __launch_bounds__(256) void prep_mm(
    const float* __restrict__ x, const float* __restrict__ Wq,
    const float* __restrict__ Wk, const float* __restrict__ Wv,
    short* __restrict__ xb, short* __restrict__ Wvt, float* __restrict__ Mp4)
{
    __shared__ short As[BM * BK], Bs[BN * BK];
    __shared__ short t[64][65];
    const int bx = blockIdx.x;
    const int tid = threadIdx.x;
    if (bx < 256) {
        const int ch = bx >> 6;            // split-k chunk, 256 wide
        const int t64 = bx & 63;
        const int m0 = (t64 >> 3) * BM;
        const int n0 = (t64 & 7) * BN;
        const int kbase = ch * 256;
        const int lane = tid & 63, wave = tid >> 6;
        f32x4 acc[4][4];
#pragma unroll
        for (int a = 0; a < 4; a++)
#pragma unroll
            for (int b = 0; b < 4; b++) acc[a][b] = (f32x4){0.f, 0.f, 0.f, 0.f};
        for (int k0 = 0; k0 < 256; k0 += BK) {
            stage_f32_128x32(Wk + (size_t)m0 * DD + kbase + k0, DD, As, tid);
            stage_f32_128x32(Wq + (size_t)n0 * DD + kbase + k0, DD, Bs, tid);
            __syncthreads();
            mfma_step(As, Bs, acc, lane, wave);
            __syncthreads();
        }
        const int wm = (wave >> 1) * 64, wn = (wave & 1) * 64;
        const int fr = lane & 15, quad = lane >> 4;
        float* Mc = Mp4 + (size_t)ch * DD * DD;
#pragma unroll
        for (int mt = 0; mt < 4; mt++)
#pragma unroll
            for (int nt = 0; nt < 4; nt++)
#pragma unroll
                for (int r = 0; r < 4; r++) {
                    const size_t m = m0 + wm + mt * 16 + quad * 4 + r;
                    const size_t n = n0 + wn + nt * 16 + fr;
                    Mc[m * DD + n] = acc[mt][nt][r];
                }
        return;
    }
    if (bx < 4352) {
        const size_t i = ((size_t)(bx - 256) * 256 + tid) * 8;
        float4 a = *(const float4*)&x[i];
        float4 b = *(const float4*)&x[i + 4];
        bf16x8 o;
        o[0] = f2bf(a.x); o[1] = f2bf(a.y); o[2] = f2bf(a.z); o[3] = f2bf(a.w);
        o[4] = f2bf(b.x); o[5] = f2bf(b.y); o[6] = f2bf(b.z); o[7] = f2bf(b.w);
        *(bf16x8*)&xb[i] = o;
        return;
    }
    const int rr = bx - 4352;
    const int k0 = (rr & 15) * 64;
    const int n0 = (rr >> 4) * 64;
    {
        const int r = tid >> 4;
        const int c = (tid & 15) * 4;
#pragma unroll
        for (int i = 0; i < 4; i++) {
            float4 v = *(const float4*)&Wv[(size_t)(k0 + i * 16 + r) * DD + n0 + c];
            t[i * 16 + r][c + 0] = f2bf(v.x);
            t[i * 16 + r][c + 1] = f2bf(v.y);
            t[i * 16 + r][c + 2] = f2bf(v.z);
            t[i * 16 + r][c + 3] = f2bf(v.w);
        }
    }
    __syncthreads();
    {
        const int r = tid >> 3;
        const int c = (tid & 7) * 8;
#pragma unroll
        for (int i = 0; i < 2; i++) {
            bf16x8 o;
#pragma unroll
            for (int j = 0; j < 8; j++) o[j] = t[c + j][i * 32 + r];
            *(bf16x8*)&Wvt[(size_t)(n0 + i * 32 + r) * DD + k0 + c] = o;
        }
    }
}

// ---------------------------------------------------------------------------
// mm_reduce: Mp[e] = bf16(sum_c Mp4[c][e]), 4 elems/thread, 1024 blocks.
// ---------------------------------------------------------------------------
__global__ __launch_bounds__(256) void mm_reduce(const float* __restrict__ Mp4,
                                                 short* __restrict__ Mp)
{
    const size_t e = ((size_t)blockIdx.x * 256 + threadIdx.x) * 4;
    const size_t N = (size_t)DD * DD;
    float4 s = *(const float4*)&Mp4[e];
#pragma unroll
    for (int c = 1; c < 4; c++) {
        float4 p = *(const float4*)&Mp4[c * N + e];
        s.x += p.x; s.y += p.y; s.z += p.z; s.w += p.w;
    }
    bf16x4 o;
    o[0] = f2bf(s.x); o[1] = f2bf(s.y); o[2] = f2bf(s.z); o[3] = f2bf(s.w);
    *(bf16x4*)&Mp[e] = o;
}

// ---------------------------------------------------------------------------
// T = xb . M'^T, row-major bf16. Lean epilogue.
// ---------------------------------------------------------------------------
__global__ __launch_bounds__(256) void t_gemm(
    const short* __restrict__ xb, const short* __restrict__ Mp,
    short* __restrict__ T)
{
    __shared__ short As[BM * BK], Bs[BN * BK];
    const int n0 = blockIdx.x * BN;
    const int m0 = blockIdx.y * BM;
    f32x4 acc[4][4];
#pragma unroll
    for (int a = 0; a < 4; a++)
#pragma unroll
        for (int b = 0; b < 4; b++) acc[a][b] = (f32x4){0.f, 0.f, 0.f, 0.f};
    gemm_bt_body(xb, DD, Mp, DD, m0, n0, DD, As, Bs, acc, threadIdx.x);
    const int lane = threadIdx.x & 63, wave = threadIdx.x >> 6;
    const int wm = (wave >> 1) * 64, wn = (wave & 1) * 64;
    const int fr = lane & 15, quad = lane >> 4;
#pragma unroll
    for (int mt = 0; mt < 4; mt++)
#pragma unroll
        for (int nt = 0; nt < 4; nt++)
#pragma unroll
            for (int r = 0; r < 4; r++) {
                const size_t m = m0 + wm + mt * 16 + quad * 4 + r;
                const size_t n = n0 + wn + nt * 16 + fr;
                T[m * DD + n] = f2bf(acc[mt][nt][r]);
            }
}

// ---------------------------------------------------------------------------
// V = xb . Wvt^T, stored TRANSPOSED directly as Vt[b][n][s].
// ---------------------------------------------------------------------------
__global__ __launch_bounds__(256) void v_gemm(
    const short* __restrict__ xb, const short* __restrict__ Wvt,
    short* __restrict__ Vt)
{
    __shared__ short As[BM * BK], Bs[BN * BK];
    const int n0 = blockIdx.x * BN;
    const int m0 = blockIdx.y * BM;
    f32x4 acc[4][4];
#pragma unroll
    for (int a = 0; a < 4; a++)
#pragma unroll
        for (int b = 0; b < 4; b++) acc[a][b] = (f32x4){0.f, 0.f, 0.f, 0.f};
    gemm_bt_body(xb, DD, Wvt, DD, m0, n0, DD, As, Bs, acc, threadIdx.x);
    const int lane = threadIdx.x & 63, wave = threadIdx.x >> 6;
    const int wm = (wave >> 1) * 64, wn = (wave & 1) * 64;
    const int fr = lane & 15, quad = lane >> 4;
    const int bb = m0 >> 11;                       // batch of this m-tile
    const int s0 = (m0 & (SB - 1)) + wm + quad * 4;
    short* Vb = Vt + (size_t)bb * DD * SB;
#pragma unroll
    for (int mt = 0; mt < 4; mt++)
#pragma unroll
        for (int nt = 0; nt < 4; nt++) {
            const size_t n = n0 + wn + nt * 16 + fr;
            const size_t s = s0 + mt * 16;
            bf16x4 o;
#pragma unroll
            for (int r = 0; r < 4; r++) o[r] = f2bf(acc[mt][nt][r]);
            *(bf16x4*)&Vb[n * SB + s] = o;
        }
}

// ---------------------------------------------------------------------------
// Scores: compact triangular grid — blockIdx.x in [0,136) -> (qt,kt), kt<=qt.
// Sc[b][q][j] = scale * T_b[q,:] . xb_b[j,:], bf16 out.
// ---------------------------------------------------------------------------
__global__ __launch_bounds__(256) void scores_mfma(
    const short* __restrict__ T, const short* __restrict__ xb,
    short* __restrict__ Sc)
{
    const int idx = blockIdx.x;
    int qt = (int)((__fsqrt_rn(8.f * idx + 1.f) - 1.f) * 0.5f);
    while ((qt + 1) * (qt + 2) / 2 <= idx) qt++;
    while (qt * (qt + 1) / 2 > idx) qt--;
    const int kt = idx - qt * (qt + 1) / 2;
    const int qm0 = qt * BM;
    const int kn0 = kt * BN;
    const int b = blockIdx.y;
    __shared__ short As[BM * BK], Bs[BN * BK];
    const short* Tb = T + (size_t)b * SB * DD;
    const short* Xb = xb + (size_t)b * SB * DD;
    short* Sb = Sc + (size_t)b * SB * SB;
    f32x4 acc[4][4];
#pragma unroll
    for (int a = 0; a < 4; a++)
#pragma unroll
        for (int c = 0; c < 4; c++) acc[a][c] = (f32x4){0.f, 0.f, 0.f, 0.f};
    gemm_bt_body(Tb, DD, Xb, DD, qm0, kn0, DD, As, Bs, acc, threadIdx.x);
    const int lane = threadIdx.x & 63, wave = threadIdx.x >> 6;
    const int wm = (wave >> 1) * 64, wn = (wave & 1) * 64;
    const int fr = lane & 15, quad = lane >> 4;
    const float scale = 0.03125f;  // 1/sqrt(1024)
#pragma unroll
    for (int mt = 0; mt < 4; mt++)
#pragma unroll
        for (int nt = 0; nt < 4; nt++)
#pragma unroll
            for (int r = 0; r < 4; r++) {
                const size_t q = qm0 + wm + mt * 16 + quad * 4 + r;
                const size_t k = kn0 + wn + nt * 16 + fr;
                Sb[q * SB + k] = f2bf(acc[mt][nt][r] * scale);
            }
}

// ---------------------------------------------------------------------------
// Causal softmax on bf16 scores, in place (row stride SB shorts). Row i only
// touches j < jlim = (i/128+1)*128 — pv reads exactly k < (qt+1)*128.
// ---------------------------------------------------------------------------
__global__ __launch_bounds__(256) void softmax_kernel(short* __restrict__ Sc)
{
    const int row = blockIdx.x;
    const int i = row & (SB - 1);
    const int jlim = ((i >> 7) + 1) << 7;
    short* r = Sc + (size_t)row * SB;
    const int t = threadIdx.x;
    const int lane = t & 63, wave = t >> 6;
    __shared__ float red[8];

    float v[8];
    float mx = -1e30f;
#pragma unroll
    for (int c = 0; c < 8; c++) {
        const int j = c * 256 + t;
        const float s = (j <= i) ? bf2f((unsigned short)r[j]) : -1e30f;
        v[c] = s;
        mx = fmaxf(mx, s);
    }
#pragma unroll
    for (int o = 32; o > 0; o >>= 1) mx = fmaxf(mx, __shfl_down(mx, o));
    if (lane == 0) red[wave] = mx;
    __syncthreads();
    mx = fmaxf(fmaxf(red[0], red[1]), fmaxf(red[2], red[3]));

    float sum = 0.f;
#pragma unroll
    for (int c = 0; c < 8; c++) {
        const int j = c * 256 + t;
        const float e = (j <= i) ? __expf(v[c] - mx) : 0.f;
        v[c] = e;
        sum += e;
    }
#pragma unroll
    for (int o = 32; o > 0; o >>= 1) sum += __shfl_down(sum, o);
    if (lane == 0) red[4 + wave] = sum;
    __syncthreads();
    const float inv = 1.0f / (red[4] + red[5] + red[6] + red[7]);
#pragma unroll
    for (int c = 0; c < 8; c++) {
        const int j = c * 256 + t;
        if (j < jlim) r[j] = f2bf(v[c] * inv);
    }
}

// ---------------------------------------------------------------------------
// PV split-k, atomic-free. blockIdx.y in [0,24):
//   y<16:  qt=y, k in [0, min(1024,(qt+1)*128))  -> store DIRECT to out
//   y>=16: qt=y-8, k in [1024, (qt+1)*128)       -> store to partial Pp
// ---------------------------------------------------------------------------
__global__ __launch_bounds__(256) void pv_mfma(
    const short* __restrict__ P, const short* __restrict__ Vt,
    float* __restrict__ O, float* __restrict__ Pp)
{
    __shared__ short As[BM * BK], Bs[BN * BK];
    const int n0 = blockIdx.x * BN;
    const int y = blockIdx.y;
    const int chunk1 = (y >= 16);
    const int qt = chunk1 ? (y - 8) : y;
    const int qm0 = qt * BM;
    const int kstart = chunk1 ? 1024 : 0;
    const int kstop = chunk1 ? (qt + 1) * BM : min(1024, (qt + 1) * BM);
    const int b = blockIdx.z;
    const short* Pb = P + (size_t)b * SB * SB + kstart;
    const short* Vb = Vt + (size_t)b * DD * SB + kstart;
    f32x4 acc[4][4];
#pragma unroll
    for (int a = 0; a < 4; a++)
#pragma unroll
        for (int c = 0; c < 4; c++) acc[a][c] = (f32x4){0.f, 0.f, 0.f, 0.f};
    gemm_bt_body(Pb, SB, Vb, SB, qm0, n0, kstop - kstart, As, Bs, acc,
                 threadIdx.x);
    const int lane = threadIdx.x & 63, wave = threadIdx.x >> 6;
    const int wm = (wave >> 1) * 64, wn = (wave & 1) * 64;
    const int fr = lane & 15, quad = lane >> 4;
    float* dst = chunk1 ? (Pp + (size_t)b * 1024 * DD)
                        : (O + (size_t)b * SB * DD);
    const int qoff = chunk1 ? 1024 : 0;
#pragma unroll
    for (int mt = 0; mt < 4; mt++)
#pragma unroll
        for (int nt = 0; nt < 4; nt++)
#pragma unroll
            for (int r = 0; r < 4; r++) {
                const size_t q = qm0 + wm + mt * 16 + quad * 4 + r - qoff;
                const size_t n = n0 + wn + nt * 16 + fr;
                dst[q * DD + n] = acc[mt][nt][r];
            }
}

// ---------------------------------------------------------------------------
// reduce: O[b][1024+q'][:] += Pp[b][q'][:], 4 floats/thread.
// ---------------------------------------------------------------------------
__global__ __launch_bounds__(256) void reduce_pv(const float* __restrict__ Pp,
                                                 float* __restrict__ O)
{
    const size_t e = ((size_t)blockIdx.x * 256 + threadIdx.x) * 4;
    const size_t b = e / ((size_t)1024 * DD);
    const size_t rem = e - b * (size_t)1024 * DD;
    float4 p = *(const float4*)&Pp[e];
    float* o = &O[b * (size_t)SB * DD + (size_t)1024 * DD + rem];
    float4 v = *(const float4*)o;
    v.x += p.x; v.y += p.y; v.z += p.z; v.w += p.w;
    *(float4*)o = v;
}

extern "C" void kernel_launch(void* const* d_in, const int* in_sizes, int n_in,
                              void* d_out, int out_size, void* d_ws, size_t ws_size,
                              hipStream_t stream)
{
    const float* x  = (const float*)d_in[0];
    const float* Wq = (const float*)d_in[1];
    const float* Wk = (const float*)d_in[2];
    const float* Wv = (const float*)d_in[3];
    float* out = (float*)d_out;

    // ws layout (~105 MB): [xb 16.8M][T 16.8M][Vt 16.8M][Sc 33.6M][Pp 16.8M]
    // [Wvt 2M][Mp 2M].  Mp4 (16.8 MB of fp32 mm partials) ALIASES the Sc
    // region: written by prep_mm, consumed by mm_reduce, then Sc overwrites
    // it in scores_mfma — all strictly ordered on the serial stream.
    const size_t XE = (size_t)NB * SB * DD;   // 8.39M elems
    const size_t WE = (size_t)DD * DD;        // 1.05M elems
    short* xb  = (short*)d_ws;
    short* T   = xb + XE;
    short* Vt  = T + XE;
    short* Sc  = Vt + XE;                     // NB*SB*SB shorts
    float* Pp  = (float*)(Sc + (size_t)NB * SB * SB);
    short* Wvt = (short*)(Pp + (size_t)NB * 1024 * DD);
    short* Mp  = Wvt + WE;
    float* Mp4 = (float*)Sc;                  // 4*WE fp32, dead before scores

    prep_mm<<<dim3(256 + 4096 + 256), 256, 0, stream>>>(
        x, Wq, Wk, Wv, xb, Wvt, Mp4);
    mm_reduce<<<dim3(1024), 256, 0, stream>>>(Mp4, Mp);
    t_gemm<<<dim3(DD / BN, (NB * SB) / BM), 256, 0, stream>>>(xb, Mp, T);
    v_gemm<<<dim3(DD / BN, (NB * SB) / BM), 256, 0, stream>>>(xb, Wvt, Vt);
    scores_mfma<<<dim3(136, NB), 256, 0, stream>>>(T, xb, Sc);
    softmax_kernel<<<dim3(NB * SB), 256, 0, stream>>>(Sc);
    pv_mfma<<<dim3(DD / BN, 24, NB), 256, 0, stream>>>(Sc, Vt, out, Pp);
    reduce_pv<<<dim3((unsigned)((size_t)NB * 1024 * DD / 4 / 256)), 256, 0,
                stream>>>(Pp, out);
}